// Round 4
// baseline (1319.245 us; speedup 1.0000x reference)
//
#include <hip/hip_runtime.h>

#define BATCH 256
#define TLEN  512
#define DIN   64
#define HID   128
#define NB    16             // batch elements per block (MFMA M)
#define NBLK  (BATCH / NB)   // 16 blocks per layer kernel
#define NOUT  40

typedef _Float16 f16x8 __attribute__((ext_vector_type(8)));
typedef float    f32x4 __attribute__((ext_vector_type(4)));

#define MFMA16(a, b, c) __builtin_amdgcn_mfma_f32_16x16x32_f16((a), (b), (c), 0, 0, 0)

// Raw barrier: LDS-visibility only. Global stores (y0) need no intra-kernel order;
// prefetch loads are waited at first use by compiler vmcnt. Avoids the full
// vmcnt(0) drain __syncthreads would emit every step.
#define BARRIER() do {                                      \
    asm volatile("s_waitcnt lgkmcnt(0)" ::: "memory");      \
    __builtin_amdgcn_s_barrier();                           \
} while (0)

static __device__ __forceinline__ f16x8 pack8(float4 a, float4 b) {
    f16x8 v;
    v[0] = (_Float16)a.x; v[1] = (_Float16)a.y; v[2] = (_Float16)a.z; v[3] = (_Float16)a.w;
    v[4] = (_Float16)b.x; v[5] = (_Float16)b.y; v[6] = (_Float16)b.z; v[7] = (_Float16)b.w;
    return v;
}
static __device__ __forceinline__ float sig_(float x) {
    return __builtin_amdgcn_rcpf(1.0f + __expf(-x));
}
static __device__ __forceinline__ float tanh_(float x) {
    // 1 - 2/(exp(2x)+1); exp->inf and ->0 limits give +-1 correctly
    return fmaf(-2.0f, __builtin_amdgcn_rcpf(__expf(2.0f * x) + 1.0f), 1.0f);
}

// Per-cell activation + cell update + h write. Expanded inside kernels; relies on
// kernel-local names acc, c_, hb, hwr. STORE_STMT may use hh (f16) / hv (f32).
#define ACT(r, WRp, STORE_STMT) do {                                            \
    float iv = sig_(acc[0][r]);  float fv = sig_(acc[1][r]);                    \
    float gv = tanh_(acc[2][r]); float ov = sig_(acc[3][r]);                    \
    c_[r] = fmaf(fv, c_[r], iv * gv);                                           \
    float hv = ov * tanh_(c_[r]);                                               \
    _Float16 hh = (_Float16)hv;                                                 \
    *(_Float16*)(&hb[WRp][0] + hwr[r]) = hh;                                    \
    STORE_STMT;                                                                 \
} while (0)

// ===================== Layer 0 =====================
// grid = 16 blocks x 512 thr (8 waves). Wave w owns hid [w*16, w*16+16).
// A rows = 16 batch elements; x enters via direct per-lane 16B global loads.
__global__ void __attribute__((amdgpu_flat_work_group_size(512, 512), amdgpu_waves_per_eu(2, 2)))
lstm_l0(const float* __restrict__ x,
        const float* __restrict__ Wih, const float* __restrict__ Whh,
        const float* __restrict__ bih, const float* __restrict__ bhh,
        _Float16* __restrict__ y0, char* __restrict__ himg, float* __restrict__ csav,
        int t0, int t1)
{
    const int tid  = threadIdx.x;
    const int lane = tid & 63, wave = tid >> 6;
    const int col  = lane & 15, kg = lane >> 4;
    const int b0   = blockIdx.x * NB;
    const int hid  = wave * 16 + col;
    const int arow = col;                      // A-fragment row = local batch

    __shared__ __align__(16) char hb[2][4096]; // h state, f16 [16][128], XOR-swizzled

    // ---- persistent weight fragments (B-operand) + bias ----
    f16x8 Wx[4][2], Wh[4][4];
    float bias[4];
    #pragma unroll
    for (int n = 0; n < 4; ++n) {
        const int g = n * HID + hid;
        #pragma unroll
        for (int kt = 0; kt < 2; ++kt) {
            const float* p = Wih + (size_t)g * DIN + kt * 32 + kg * 8;
            Wx[n][kt] = pack8(*(const float4*)p, *(const float4*)(p + 4));
        }
        #pragma unroll
        for (int kt = 0; kt < 4; ++kt) {
            const float* p = Whh + (size_t)g * HID + kt * 32 + kg * 8;
            Wh[n][kt] = pack8(*(const float4*)p, *(const float4*)(p + 4));
        }
        bias[n] = bih[g] + bhh[g];
    }

    // ---- c state (4 rows per lane) ----
    float c_[4];
    #pragma unroll
    for (int r = 0; r < 4; ++r) c_[r] = csav[(size_t)(b0 + kg * 4 + r) * HID + hid];

    // ---- LDS addresses (precomputed, loop-invariant) ----
    const int xsw = (arow & 7) << 4;
    int hrd[4], hwr[4], yof[4];
    #pragma unroll
    for (int kt = 0; kt < 4; ++kt) hrd[kt] = (arow * 256 + kt * 64 + kg * 16) ^ xsw;
    #pragma unroll
    for (int r = 0; r < 4; ++r) {
        const int row = kg * 4 + r;
        hwr[r] = (row * 256 + hid * 2) ^ ((row & 7) << 4);
        yof[r] = (b0 + row) * HID + hid;
    }

    // ---- restore h image, issue first x loads ----
    *(uint2*)(&hb[0][0] + tid * 8) = ((const uint2*)(himg + (size_t)blockIdx.x * 4096))[tid];
    const size_t xbase = (size_t)(b0 + arow) * TLEN * DIN;
    const int xo0 = kg * 2, xo1 = kg * 2 + 8;      // float4 indices within 64-elem row
    float4 xA0, xA1, xA2, xA3, xB0, xB1, xB2, xB3;
    {
        const float4* xp = (const float4*)(x + xbase + (size_t)t0 * DIN);
        xA0 = xp[xo0]; xA1 = xp[xo0 + 1]; xA2 = xp[xo1]; xA3 = xp[xo1 + 1];
    }
    BARRIER();

#define L0_STEP(T, RD, WR, XC0, XC1, XC2, XC3, XN0, XN1, XN2, XN3) do {          \
    f16x8 xa[2];                                                                 \
    xa[0] = pack8(XC0, XC1); xa[1] = pack8(XC2, XC3);                            \
    { int tn = (T) + 1; if (tn > TLEN - 1) tn = TLEN - 1;                        \
      const float4* xp = (const float4*)(x + xbase + (size_t)tn * DIN);          \
      XN0 = xp[xo0]; XN1 = xp[xo0 + 1]; XN2 = xp[xo1]; XN3 = xp[xo1 + 1]; }      \
    f16x8 ha[4];                                                                 \
    _Pragma("unroll") for (int kt = 0; kt < 4; ++kt)                             \
        ha[kt] = *(const f16x8*)(&hb[RD][0] + hrd[kt]);                          \
    f32x4 acc[4];                                                                \
    _Pragma("unroll") for (int n = 0; n < 4; ++n)                                \
        acc[n] = (f32x4){bias[n], bias[n], bias[n], bias[n]};                    \
    _Pragma("unroll") for (int n = 0; n < 4; ++n) {                              \
        _Pragma("unroll") for (int kt = 0; kt < 2; ++kt)                         \
            acc[n] = MFMA16(xa[kt], Wx[n][kt], acc[n]);                          \
        _Pragma("unroll") for (int kt = 0; kt < 4; ++kt)                         \
            acc[n] = MFMA16(ha[kt], Wh[n][kt], acc[n]);                          \
    }                                                                            \
    _Float16* yrow = y0 + (size_t)((T) - t0) * (BATCH * HID);                    \
    ACT(0, WR, yrow[yof[0]] = hh);                                               \
    ACT(1, WR, yrow[yof[1]] = hh);                                               \
    ACT(2, WR, yrow[yof[2]] = hh);                                               \
    ACT(3, WR, yrow[yof[3]] = hh);                                               \
    BARRIER();                                                                   \
} while (0)

    const int nt = t1 - t0;   // even by construction
    for (int s = 0; s + 1 < nt; s += 2) {
        L0_STEP(t0 + s,     0, 1, xA0, xA1, xA2, xA3, xB0, xB1, xB2, xB3);
        L0_STEP(t0 + s + 1, 1, 0, xB0, xB1, xB2, xB3, xA0, xA1, xA2, xA3);
    }
#undef L0_STEP

    // ---- persist state (final h image is in buf 0 since nt is even) ----
    #pragma unroll
    for (int r = 0; r < 4; ++r) csav[(size_t)(b0 + kg * 4 + r) * HID + hid] = c_[r];
    ((uint2*)(himg + (size_t)blockIdx.x * 4096))[tid] = *(uint2*)(&hb[0][0] + tid * 8);
}

// ===================== Layer 1 =====================
__global__ void __attribute__((amdgpu_flat_work_group_size(512, 512), amdgpu_waves_per_eu(2, 2)))
lstm_l1(const _Float16* __restrict__ y0in,
        const float* __restrict__ Wih, const float* __restrict__ Whh,
        const float* __restrict__ bih, const float* __restrict__ bhh,
        char* __restrict__ himg, float* __restrict__ csav, float* __restrict__ h1g,
        int t0, int t1)
{
    const int tid  = threadIdx.x;
    const int lane = tid & 63, wave = tid >> 6;
    const int col  = lane & 15, kg = lane >> 4;
    const int b0   = blockIdx.x * NB;
    const int hid  = wave * 16 + col;
    const int arow = col;

    __shared__ __align__(16) char hb[2][4096];

    f16x8 Wy[4][4], Wh[4][4];
    float bias[4];
    #pragma unroll
    for (int n = 0; n < 4; ++n) {
        const int g = n * HID + hid;
        #pragma unroll
        for (int kt = 0; kt < 4; ++kt) {
            const float* p = Wih + (size_t)g * HID + kt * 32 + kg * 8;
            Wy[n][kt] = pack8(*(const float4*)p, *(const float4*)(p + 4));
        }
        #pragma unroll
        for (int kt = 0; kt < 4; ++kt) {
            const float* p = Whh + (size_t)g * HID + kt * 32 + kg * 8;
            Wh[n][kt] = pack8(*(const float4*)p, *(const float4*)(p + 4));
        }
        bias[n] = bih[g] + bhh[g];
    }

    float c_[4];
    #pragma unroll
    for (int r = 0; r < 4; ++r) c_[r] = csav[(size_t)(b0 + kg * 4 + r) * HID + hid];

    const int xsw = (arow & 7) << 4;
    int hrd[4], hwr[4];
    #pragma unroll
    for (int kt = 0; kt < 4; ++kt) hrd[kt] = (arow * 256 + kt * 64 + kg * 16) ^ xsw;
    #pragma unroll
    for (int r = 0; r < 4; ++r) {
        const int row = kg * 4 + r;
        hwr[r] = (row * 256 + hid * 2) ^ ((row & 7) << 4);
    }

    float hsav[4] = {0.f, 0.f, 0.f, 0.f};

    *(uint2*)(&hb[0][0] + tid * 8) = ((const uint2*)(himg + (size_t)blockIdx.x * 4096))[tid];
    const size_t ybase = (size_t)(b0 + arow) * HID + kg * 8;   // f16 elems
    uint4 yA[4], yB[4];
    {
        const uint4* yp = (const uint4*)(y0in + ybase);        // rel = 0
        #pragma unroll
        for (int kt = 0; kt < 4; ++kt) yA[kt] = yp[kt * 4];
    }
    BARRIER();

#define L1_STEP(T, RD, WR, YC, YN) do {                                          \
    f16x8 ya[4];                                                                 \
    _Pragma("unroll") for (int kt = 0; kt < 4; ++kt)                             \
        ya[kt] = __builtin_bit_cast(f16x8, YC[kt]);                              \
    { int tn = (T) + 1; if (tn > t1 - 1) tn = t1 - 1;                            \
      const uint4* yp = (const uint4*)(y0in + (size_t)(tn - t0) * (BATCH * HID) + ybase); \
      _Pragma("unroll") for (int kt = 0; kt < 4; ++kt) YN[kt] = yp[kt * 4]; }    \
    f16x8 ha[4];                                                                 \
    _Pragma("unroll") for (int kt = 0; kt < 4; ++kt)                             \
        ha[kt] = *(const f16x8*)(&hb[RD][0] + hrd[kt]);                          \
    f32x4 acc[4];                                                                \
    _Pragma("unroll") for (int n = 0; n < 4; ++n)                                \
        acc[n] = (f32x4){bias[n], bias[n], bias[n], bias[n]};                    \
    _Pragma("unroll") for (int n = 0; n < 4; ++n) {                              \
        _Pragma("unroll") for (int kt = 0; kt < 4; ++kt)                         \
            acc[n] = MFMA16(ya[kt], Wy[n][kt], acc[n]);                          \
        _Pragma("unroll") for (int kt = 0; kt < 4; ++kt)                         \
            acc[n] = MFMA16(ha[kt], Wh[n][kt], acc[n]);                          \
    }                                                                            \
    ACT(0, WR, hsav[0] = hv);                                                    \
    ACT(1, WR, hsav[1] = hv);                                                    \
    ACT(2, WR, hsav[2] = hv);                                                    \
    ACT(3, WR, hsav[3] = hv);                                                    \
    BARRIER();                                                                   \
} while (0)

    const int nt = t1 - t0;
    for (int s = 0; s + 1 < nt; s += 2) {
        L1_STEP(t0 + s,     0, 1, yA, yB);
        L1_STEP(t0 + s + 1, 1, 0, yB, yA);
    }
#undef L1_STEP

    #pragma unroll
    for (int r = 0; r < 4; ++r) {
        csav[(size_t)(b0 + kg * 4 + r) * HID + hid] = c_[r];
        h1g[(size_t)(b0 + kg * 4 + r) * HID + hid]  = hsav[r];
    }
    ((uint2*)(himg + (size_t)blockIdx.x * 4096))[tid] = *(uint2*)(&hb[0][0] + tid * 8);
}

// ===================== Final FC =====================
__global__ __launch_bounds__(128) void fc_kernel(
    const float* __restrict__ h1, const float* __restrict__ Wfc,
    const float* __restrict__ bfc, float* __restrict__ out)
{
    const int b = blockIdx.x;
    const int o = threadIdx.x;
    __shared__ float hs[HID];
    hs[o] = h1[b * HID + o];
    __syncthreads();
    if (o < NOUT) {
        const float4* w  = reinterpret_cast<const float4*>(Wfc + (size_t)o * HID);
        const float4* hv = reinterpret_cast<const float4*>(hs);
        float acc = bfc[o];
        #pragma unroll
        for (int q = 0; q < HID / 4; ++q) {
            float4 wv = w[q]; float4 h4 = hv[q];
            acc = fmaf(wv.x, h4.x, fmaf(wv.y, h4.y, fmaf(wv.z, h4.z, fmaf(wv.w, h4.w, acc))));
        }
        out[b * NOUT + o] = acc;
    }
}

extern "C" void kernel_launch(void* const* d_in, const int* in_sizes, int n_in,
                              void* d_out, int out_size, void* d_ws, size_t ws_size,
                              hipStream_t stream) {
    const float* x    = (const float*)d_in[0];
    const float* Wih0 = (const float*)d_in[1];
    const float* Whh0 = (const float*)d_in[2];
    const float* bih0 = (const float*)d_in[3];
    const float* bhh0 = (const float*)d_in[4];
    const float* Wih1 = (const float*)d_in[5];
    const float* Whh1 = (const float*)d_in[6];
    const float* bih1 = (const float*)d_in[7];
    const float* bhh1 = (const float*)d_in[8];
    const float* Wfc  = (const float*)d_in[9];
    const float* bfc  = (const float*)d_in[10];
    float* out = (float*)d_out;

    // ws layout: himg0 64K | himg1 64K | csav0 128K | csav1 128K | h1g 128K | y0 slab
    char*  himg0 = (char*)d_ws;
    char*  himg1 = himg0 + (64 << 10);
    float* csav0 = (float*)(himg1 + (64 << 10));
    float* csav1 = csav0 + BATCH * HID;
    float* h1g   = csav1 + BATCH * HID;
    _Float16* y0 = (_Float16*)(h1g + BATCH * HID);

    const size_t stateBytes = (size_t)(64 + 64 + 128 + 128 + 128) << 10;   // 512 KB
    size_t avail = ws_size > stateBytes ? ws_size - stateBytes : 0;
    int Tc = (int)(avail / ((size_t)BATCH * HID * 2));
    if (Tc > TLEN) Tc = TLEN;
    Tc &= ~1;
    if (Tc < 2) Tc = 2;

    hipMemsetAsync(d_ws, 0, stateBytes, stream);

    for (int t0 = 0; t0 < TLEN; t0 += Tc) {
        int t1 = t0 + Tc; if (t1 > TLEN) t1 = TLEN;
        lstm_l0<<<NBLK, 512, 0, stream>>>(x, Wih0, Whh0, bih0, bhh0, y0, himg0, csav0, t0, t1);
        lstm_l1<<<NBLK, 512, 0, stream>>>(y0, Wih1, Whh1, bih1, bhh1, himg1, csav1, h1g, t0, t1);
    }
    fc_kernel<<<BATCH, 128, 0, stream>>>(h1g, Wfc, bfc, out);
}

// Round 5
// 656.794 us; speedup vs baseline: 2.0086x; 2.0086x over previous
//
#include <hip/hip_runtime.h>

#define BATCH 256
#define TLEN  512
#define DIN   64
#define HID   128
#define NOUT  40

typedef _Float16 f16x8 __attribute__((ext_vector_type(8)));
typedef _Float16 f16x4 __attribute__((ext_vector_type(4)));
typedef float    f32x4 __attribute__((ext_vector_type(4)));

#define MFMA16(a, b, c) __builtin_amdgcn_mfma_f32_16x16x32_f16((a), (b), (c), 0, 0, 0)

// LDS-visibility barrier only: no vmcnt drain (prefetch loads are waited at
// first use; y0 stores need no intra-kernel ordering).
#define BARRIER() do {                                      \
    asm volatile("s_waitcnt lgkmcnt(0)" ::: "memory");      \
    __builtin_amdgcn_s_barrier();                           \
} while (0)

static __device__ __forceinline__ f16x8 pack8(float4 a, float4 b) {
    f16x8 v;
    v[0] = (_Float16)a.x; v[1] = (_Float16)a.y; v[2] = (_Float16)a.z; v[3] = (_Float16)a.w;
    v[4] = (_Float16)b.x; v[5] = (_Float16)b.y; v[6] = (_Float16)b.z; v[7] = (_Float16)b.w;
    return v;
}
static __device__ __forceinline__ float sig_(float x) {
    return __builtin_amdgcn_rcpf(1.0f + __expf(-x));
}
static __device__ __forceinline__ float tanh_(float x) {
    return fmaf(-2.0f, __builtin_amdgcn_rcpf(__expf(2.0f * x) + 1.0f), 1.0f);
}

// ===================== Layer 0 =====================
// 256 blocks (one batch element each) x 512 thr (8 waves).
// Wave w owns hid [w*16, w*16+16) and all 4 gate types for it (in-wave ACT).
// A-operand = x/h replicated rows (broadcast LDS reads); B = weight fragments.
__global__ void __attribute__((amdgpu_flat_work_group_size(512, 512), amdgpu_waves_per_eu(2, 2)))
lstm_l0(const float* __restrict__ x,
        const float* __restrict__ Wih, const float* __restrict__ Whh,
        const float* __restrict__ bih, const float* __restrict__ bhh,
        float* __restrict__ hstate, float* __restrict__ cstate,
        _Float16* __restrict__ y0, int t0, int t1)
{
    const int b    = blockIdx.x;
    const int tid  = threadIdx.x;
    const int lane = tid & 63, wave = tid >> 6;
    const int col  = lane & 15, kg = lane >> 4;
    const int hid  = wave * 16 + col;

    __shared__ __align__(16) _Float16 x_lds[2][DIN];
    __shared__ __align__(16) _Float16 h_lds[2][HID];

    // ---- persistent weight B-fragments: k = kt*32 + kg*8 + j ----
    f16x8 Wx[4][2], Wh[4][4];
    float bias[4];
    #pragma unroll
    for (int n = 0; n < 4; ++n) {
        const int g = n * HID + hid;
        #pragma unroll
        for (int kt = 0; kt < 2; ++kt) {
            const float* p = Wih + (size_t)g * DIN + kt * 32 + kg * 8;
            Wx[n][kt] = pack8(*(const float4*)p, *(const float4*)(p + 4));
        }
        #pragma unroll
        for (int kt = 0; kt < 4; ++kt) {
            const float* p = Whh + (size_t)g * HID + kt * 32 + kg * 8;
            Wh[n][kt] = pack8(*(const float4*)p, *(const float4*)(p + 4));
        }
        bias[n] = bih[g] + bhh[g];
    }

    float cc = cstate[(size_t)b * HID + hid];          // all kg duplicates
    float hv = hstate[(size_t)b * HID + hid];
    if (kg == 0) h_lds[0][hid] = (_Float16)hv;

    // ---- x loaders: wave 7 lanes 0..15, coalesced float4, distance-2 prefetch ----
    const float4* xrow = (const float4*)(x + (size_t)b * TLEN * DIN);
    const int lk = tid - 448;                          // 0..15 for loaders
    const bool ldr = ((unsigned)lk < 16u);
    float4 xpfA = make_float4(0, 0, 0, 0), xpfB = xpfA;
    if (ldr) {
        float4 v = xrow[(size_t)t0 * (DIN / 4) + lk];
        f16x4 pw; pw[0] = (_Float16)v.x; pw[1] = (_Float16)v.y;
        pw[2] = (_Float16)v.z; pw[3] = (_Float16)v.w;
        *(f16x4*)&x_lds[0][lk * 4] = pw;
        int ta = t0 + 1 < TLEN ? t0 + 1 : TLEN - 1;
        int tb = t0 + 2 < TLEN ? t0 + 2 : TLEN - 1;
        xpfA = xrow[(size_t)ta * (DIN / 4) + lk];
        xpfB = xrow[(size_t)tb * (DIN / 4) + lk];
    }
    BARRIER();

#define L0_STEP(T, P, XPF) do {                                                  \
    if (ldr) {                                                                   \
        f16x4 pw; pw[0] = (_Float16)XPF.x; pw[1] = (_Float16)XPF.y;              \
        pw[2] = (_Float16)XPF.z; pw[3] = (_Float16)XPF.w;                        \
        *(f16x4*)&x_lds[(P) ^ 1][lk * 4] = pw;                                   \
        int tn = (T) + 3; if (tn > TLEN - 1) tn = TLEN - 1;                      \
        XPF = xrow[(size_t)tn * (DIN / 4) + lk];                                 \
    }                                                                            \
    f16x8 xa0 = *(const f16x8*)&x_lds[P][kg * 8];                                \
    f16x8 xa1 = *(const f16x8*)&x_lds[P][32 + kg * 8];                           \
    f16x8 ha0 = *(const f16x8*)&h_lds[P][kg * 8];                                \
    f16x8 ha1 = *(const f16x8*)&h_lds[P][32 + kg * 8];                           \
    f16x8 ha2 = *(const f16x8*)&h_lds[P][64 + kg * 8];                           \
    f16x8 ha3 = *(const f16x8*)&h_lds[P][96 + kg * 8];                           \
    f32x4 a0 = {bias[0], bias[0], bias[0], bias[0]};                             \
    f32x4 a1 = {bias[1], bias[1], bias[1], bias[1]};                             \
    f32x4 a2 = {bias[2], bias[2], bias[2], bias[2]};                             \
    f32x4 a3 = {bias[3], bias[3], bias[3], bias[3]};                             \
    a0 = MFMA16(xa0, Wx[0][0], a0); a1 = MFMA16(xa0, Wx[1][0], a1);              \
    a2 = MFMA16(xa0, Wx[2][0], a2); a3 = MFMA16(xa0, Wx[3][0], a3);              \
    a0 = MFMA16(xa1, Wx[0][1], a0); a1 = MFMA16(xa1, Wx[1][1], a1);              \
    a2 = MFMA16(xa1, Wx[2][1], a2); a3 = MFMA16(xa1, Wx[3][1], a3);              \
    a0 = MFMA16(ha0, Wh[0][0], a0); a1 = MFMA16(ha0, Wh[1][0], a1);              \
    a2 = MFMA16(ha0, Wh[2][0], a2); a3 = MFMA16(ha0, Wh[3][0], a3);              \
    a0 = MFMA16(ha1, Wh[0][1], a0); a1 = MFMA16(ha1, Wh[1][1], a1);              \
    a2 = MFMA16(ha1, Wh[2][1], a2); a3 = MFMA16(ha1, Wh[3][1], a3);              \
    a0 = MFMA16(ha2, Wh[0][2], a0); a1 = MFMA16(ha2, Wh[1][2], a1);              \
    a2 = MFMA16(ha2, Wh[2][2], a2); a3 = MFMA16(ha2, Wh[3][2], a3);              \
    a0 = MFMA16(ha3, Wh[0][3], a0); a1 = MFMA16(ha3, Wh[1][3], a1);              \
    a2 = MFMA16(ha3, Wh[2][3], a2); a3 = MFMA16(ha3, Wh[3][3], a3);              \
    float iv = sig_(a0[0]), fv = sig_(a1[0]);                                    \
    float gv = tanh_(a2[0]), ov = sig_(a3[0]);                                   \
    cc = fmaf(fv, cc, iv * gv);                                                  \
    hv = ov * tanh_(cc);                                                         \
    _Float16 hh = (_Float16)hv;                                                  \
    if (kg == 0) {                                                               \
        h_lds[(P) ^ 1][hid] = hh;                                                \
        y0[((size_t)((T) - t0) * BATCH + b) * HID + hid] = hh;                   \
    }                                                                            \
    BARRIER();                                                                   \
} while (0)

    const int nt = t1 - t0;                            // even by construction
    for (int s = 0; s + 1 < nt; s += 2) {
        L0_STEP(t0 + s,     0, xpfA);
        L0_STEP(t0 + s + 1, 1, xpfB);
    }
#undef L0_STEP

    if (kg == 0) {
        cstate[(size_t)b * HID + hid] = cc;
        hstate[(size_t)b * HID + hid] = hv;
    }
}

// ===================== Layer 1 =====================
__global__ void __attribute__((amdgpu_flat_work_group_size(512, 512), amdgpu_waves_per_eu(2, 2)))
lstm_l1(const _Float16* __restrict__ y0in,
        const float* __restrict__ Wih, const float* __restrict__ Whh,
        const float* __restrict__ bih, const float* __restrict__ bhh,
        float* __restrict__ hstate, float* __restrict__ cstate,
        int t0, int t1)
{
    const int b    = blockIdx.x;
    const int tid  = threadIdx.x;
    const int lane = tid & 63, wave = tid >> 6;
    const int col  = lane & 15, kg = lane >> 4;
    const int hid  = wave * 16 + col;

    __shared__ __align__(16) _Float16 y_lds[2][HID];
    __shared__ __align__(16) _Float16 h_lds[2][HID];

    f16x8 Wy[4][4], Wh[4][4];
    float bias[4];
    #pragma unroll
    for (int n = 0; n < 4; ++n) {
        const int g = n * HID + hid;
        #pragma unroll
        for (int kt = 0; kt < 4; ++kt) {
            const float* p = Wih + (size_t)g * HID + kt * 32 + kg * 8;
            Wy[n][kt] = pack8(*(const float4*)p, *(const float4*)(p + 4));
        }
        #pragma unroll
        for (int kt = 0; kt < 4; ++kt) {
            const float* p = Whh + (size_t)g * HID + kt * 32 + kg * 8;
            Wh[n][kt] = pack8(*(const float4*)p, *(const float4*)(p + 4));
        }
        bias[n] = bih[g] + bhh[g];
    }

    float cc = cstate[(size_t)b * HID + hid];
    float hv = hstate[(size_t)b * HID + hid];
    if (kg == 0) h_lds[0][hid] = (_Float16)hv;

    // y0 loaders: wave 7 lanes 0..15, one uint4 (8 f16) each, coalesced 256B/row
    const uint4* yrow = (const uint4*)(y0in);
    const int lk = tid - 448;
    const bool ldr = ((unsigned)lk < 16u);
    const int nt = t1 - t0;
    uint4 ypfA = make_uint4(0, 0, 0, 0), ypfB = ypfA;
    if (ldr) {
        *(uint4*)&y_lds[0][lk * 8] = yrow[((size_t)0 * BATCH + b) * (HID / 8) + lk];
        int ra = 1 < nt - 1 ? 1 : nt - 1;
        int rb = 2 < nt - 1 ? 2 : nt - 1;
        ypfA = yrow[((size_t)ra * BATCH + b) * (HID / 8) + lk];
        ypfB = yrow[((size_t)rb * BATCH + b) * (HID / 8) + lk];
    }
    BARRIER();

#define L1_STEP(REL, P, YPF) do {                                                \
    if (ldr) {                                                                   \
        *(uint4*)&y_lds[(P) ^ 1][lk * 8] = YPF;                                  \
        int rn = (REL) + 3; if (rn > nt - 1) rn = nt - 1;                        \
        YPF = yrow[((size_t)rn * BATCH + b) * (HID / 8) + lk];                   \
    }                                                                            \
    f16x8 ya0 = *(const f16x8*)&y_lds[P][kg * 8];                                \
    f16x8 ya1 = *(const f16x8*)&y_lds[P][32 + kg * 8];                           \
    f16x8 ya2 = *(const f16x8*)&y_lds[P][64 + kg * 8];                           \
    f16x8 ya3 = *(const f16x8*)&y_lds[P][96 + kg * 8];                           \
    f16x8 ha0 = *(const f16x8*)&h_lds[P][kg * 8];                                \
    f16x8 ha1 = *(const f16x8*)&h_lds[P][32 + kg * 8];                           \
    f16x8 ha2 = *(const f16x8*)&h_lds[P][64 + kg * 8];                           \
    f16x8 ha3 = *(const f16x8*)&h_lds[P][96 + kg * 8];                           \
    f32x4 a0 = {bias[0], bias[0], bias[0], bias[0]};                             \
    f32x4 a1 = {bias[1], bias[1], bias[1], bias[1]};                             \
    f32x4 a2 = {bias[2], bias[2], bias[2], bias[2]};                             \
    f32x4 a3 = {bias[3], bias[3], bias[3], bias[3]};                             \
    a0 = MFMA16(ya0, Wy[0][0], a0); a1 = MFMA16(ya0, Wy[1][0], a1);              \
    a2 = MFMA16(ya0, Wy[2][0], a2); a3 = MFMA16(ya0, Wy[3][0], a3);              \
    a0 = MFMA16(ya1, Wy[0][1], a0); a1 = MFMA16(ya1, Wy[1][1], a1);              \
    a2 = MFMA16(ya1, Wy[2][1], a2); a3 = MFMA16(ya1, Wy[3][1], a3);              \
    a0 = MFMA16(ya2, Wy[0][2], a0); a1 = MFMA16(ya2, Wy[1][2], a1);              \
    a2 = MFMA16(ya2, Wy[2][2], a2); a3 = MFMA16(ya2, Wy[3][2], a3);              \
    a0 = MFMA16(ya3, Wy[0][3], a0); a1 = MFMA16(ya3, Wy[1][3], a1);              \
    a2 = MFMA16(ya3, Wy[2][3], a2); a3 = MFMA16(ya3, Wy[3][3], a3);              \
    a0 = MFMA16(ha0, Wh[0][0], a0); a1 = MFMA16(ha0, Wh[1][0], a1);              \
    a2 = MFMA16(ha0, Wh[2][0], a2); a3 = MFMA16(ha0, Wh[3][0], a3);              \
    a0 = MFMA16(ha1, Wh[0][1], a0); a1 = MFMA16(ha1, Wh[1][1], a1);              \
    a2 = MFMA16(ha1, Wh[2][1], a2); a3 = MFMA16(ha1, Wh[3][1], a3);              \
    a0 = MFMA16(ha2, Wh[0][2], a0); a1 = MFMA16(ha2, Wh[1][2], a1);              \
    a2 = MFMA16(ha2, Wh[2][2], a2); a3 = MFMA16(ha2, Wh[3][2], a3);              \
    a0 = MFMA16(ha3, Wh[0][3], a0); a1 = MFMA16(ha3, Wh[1][3], a1);              \
    a2 = MFMA16(ha3, Wh[2][3], a2); a3 = MFMA16(ha3, Wh[3][3], a3);              \
    float iv = sig_(a0[0]), fv = sig_(a1[0]);                                    \
    float gv = tanh_(a2[0]), ov = sig_(a3[0]);                                   \
    cc = fmaf(fv, cc, iv * gv);                                                  \
    hv = ov * tanh_(cc);                                                         \
    if (kg == 0) h_lds[(P) ^ 1][hid] = (_Float16)hv;                             \
    BARRIER();                                                                   \
} while (0)

    for (int s = 0; s + 1 < nt; s += 2) {
        L1_STEP(s,     0, ypfA);
        L1_STEP(s + 1, 1, ypfB);
    }
#undef L1_STEP

    if (kg == 0) {
        cstate[(size_t)b * HID + hid] = cc;
        hstate[(size_t)b * HID + hid] = hv;   // final h1 (fc reads this)
    }
}

// ===================== Final FC =====================
__global__ __launch_bounds__(128) void fc_kernel(
    const float* __restrict__ h1, const float* __restrict__ Wfc,
    const float* __restrict__ bfc, float* __restrict__ out)
{
    const int b = blockIdx.x;
    const int o = threadIdx.x;
    __shared__ float hs[HID];
    hs[o] = h1[(size_t)b * HID + o];
    __syncthreads();
    if (o < NOUT) {
        const float4* w  = reinterpret_cast<const float4*>(Wfc + (size_t)o * HID);
        const float4* hv = reinterpret_cast<const float4*>(hs);
        float acc = bfc[o];
        #pragma unroll
        for (int q = 0; q < HID / 4; ++q) {
            float4 wv = w[q]; float4 h4 = hv[q];
            acc = fmaf(wv.x, h4.x, fmaf(wv.y, h4.y, fmaf(wv.z, h4.z, fmaf(wv.w, h4.w, acc))));
        }
        out[(size_t)b * NOUT + o] = acc;
    }
}

extern "C" void kernel_launch(void* const* d_in, const int* in_sizes, int n_in,
                              void* d_out, int out_size, void* d_ws, size_t ws_size,
                              hipStream_t stream) {
    const float* x    = (const float*)d_in[0];
    const float* Wih0 = (const float*)d_in[1];
    const float* Whh0 = (const float*)d_in[2];
    const float* bih0 = (const float*)d_in[3];
    const float* bhh0 = (const float*)d_in[4];
    const float* Wih1 = (const float*)d_in[5];
    const float* Whh1 = (const float*)d_in[6];
    const float* bih1 = (const float*)d_in[7];
    const float* bhh1 = (const float*)d_in[8];
    const float* Wfc  = (const float*)d_in[9];
    const float* bfc  = (const float*)d_in[10];
    float* out = (float*)d_out;

    // ws: hst0 | cst0 | hst1 | cst1 (f32, 128KB each) then y0 slab (f16)
    float* hst0 = (float*)d_ws;
    float* cst0 = hst0 + BATCH * HID;
    float* hst1 = cst0 + BATCH * HID;
    float* cst1 = hst1 + BATCH * HID;
    _Float16* y0 = (_Float16*)(cst1 + BATCH * HID);

    const size_t stateBytes = (size_t)4 * BATCH * HID * sizeof(float);   // 512 KB
    size_t avail = ws_size > stateBytes ? ws_size - stateBytes : 0;
    int Tc = (int)(avail / ((size_t)BATCH * HID * 2));
    if (Tc > TLEN) Tc = TLEN;
    Tc &= ~1;
    if (Tc < 2) Tc = 2;

    hipMemsetAsync(d_ws, 0, stateBytes, stream);

    for (int t0 = 0; t0 < TLEN; t0 += Tc) {
        int t1 = t0 + Tc; if (t1 > TLEN) t1 = TLEN;
        lstm_l0<<<BATCH, 512, 0, stream>>>(x, Wih0, Whh0, bih0, bhh0, hst0, cst0, y0, t0, t1);
        lstm_l1<<<BATCH, 512, 0, stream>>>(y0, Wih1, Whh1, bih1, bhh1, hst1, cst1, t0, t1);
    }
    fc_kernel<<<BATCH, 128, 0, stream>>>(hst1, Wfc, bfc, out);
}

// Round 6
// 655.819 us; speedup vs baseline: 2.0116x; 1.0015x over previous
//
#include <hip/hip_runtime.h>

#define BATCH 256
#define TLEN  512
#define DIN   64
#define HID   128
#define NOUT  40

typedef _Float16 f16x8 __attribute__((ext_vector_type(8)));
typedef _Float16 f16x4 __attribute__((ext_vector_type(4)));
typedef float    f32x4 __attribute__((ext_vector_type(4)));

#define MFMA16(a, b, c) __builtin_amdgcn_mfma_f32_16x16x32_f16((a), (b), (c), 0, 0, 0)

// LDS-visibility barrier only: no vmcnt drain (prefetch loads are waited at
// first use; y0 stores need no intra-kernel ordering).
#define BARRIER() do {                                      \
    asm volatile("s_waitcnt lgkmcnt(0)" ::: "memory");      \
    __builtin_amdgcn_s_barrier();                           \
} while (0)

static __device__ __forceinline__ f16x8 pack8(float4 a, float4 b) {
    f16x8 v;
    v[0] = (_Float16)a.x; v[1] = (_Float16)a.y; v[2] = (_Float16)a.z; v[3] = (_Float16)a.w;
    v[4] = (_Float16)b.x; v[5] = (_Float16)b.y; v[6] = (_Float16)b.z; v[7] = (_Float16)b.w;
    return v;
}
static __device__ __forceinline__ float sig_(float x) {
    return __builtin_amdgcn_rcpf(1.0f + __expf(-x));
}
static __device__ __forceinline__ float tanh_(float x) {
    return fmaf(-2.0f, __builtin_amdgcn_rcpf(__expf(2.0f * x) + 1.0f), 1.0f);
}

// Weight fragment loader; uses kernel-local `kg`. k = kt*32 + kg*8 + j.
#define LD8(base, g, K, kt) pack8(*(const float4*)((base) + (size_t)(g) * (K) + (kt) * 32 + kg * 8), \
                                  *(const float4*)((base) + (size_t)(g) * (K) + (kt) * 32 + kg * 8 + 4))

// ===================== Layer 0 =====================
// 256 blocks (one batch element) x 512 thr (8 waves). Wave w owns hid
// [w*16,w*16+16) and all 4 gate tiles for it (in-wave ACT, no gate exchange).
// Weights pinned in AGPRs (MFMA reads them in place); working set in VGPRs.
__global__ void __attribute__((amdgpu_flat_work_group_size(512, 512), amdgpu_waves_per_eu(2, 2)))
lstm_l0(const float* __restrict__ x,
        const float* __restrict__ Wih, const float* __restrict__ Whh,
        const float* __restrict__ bih, const float* __restrict__ bhh,
        float* __restrict__ hstate, float* __restrict__ cstate,
        _Float16* __restrict__ y0, int t0, int t1)
{
    const int b    = blockIdx.x;
    const int tid  = threadIdx.x;
    const int lane = tid & 63, wave = tid >> 6;
    const int col  = lane & 15, kg = lane >> 4;
    const int hid  = wave * 16 + col;

    __shared__ __align__(16) _Float16 x_lds[2][DIN];
    __shared__ __align__(16) _Float16 h_lds[2][HID];

    // ---- weight fragments -> AGPR-pinned ----
    f16x8 Wx00 = LD8(Wih, 0 * HID + hid, DIN, 0), Wx01 = LD8(Wih, 0 * HID + hid, DIN, 1);
    f16x8 Wx10 = LD8(Wih, 1 * HID + hid, DIN, 0), Wx11 = LD8(Wih, 1 * HID + hid, DIN, 1);
    f16x8 Wx20 = LD8(Wih, 2 * HID + hid, DIN, 0), Wx21 = LD8(Wih, 2 * HID + hid, DIN, 1);
    f16x8 Wx30 = LD8(Wih, 3 * HID + hid, DIN, 0), Wx31 = LD8(Wih, 3 * HID + hid, DIN, 1);
    f16x8 Wh00 = LD8(Whh, 0 * HID + hid, HID, 0), Wh01 = LD8(Whh, 0 * HID + hid, HID, 1);
    f16x8 Wh02 = LD8(Whh, 0 * HID + hid, HID, 2), Wh03 = LD8(Whh, 0 * HID + hid, HID, 3);
    f16x8 Wh10 = LD8(Whh, 1 * HID + hid, HID, 0), Wh11 = LD8(Whh, 1 * HID + hid, HID, 1);
    f16x8 Wh12 = LD8(Whh, 1 * HID + hid, HID, 2), Wh13 = LD8(Whh, 1 * HID + hid, HID, 3);
    f16x8 Wh20 = LD8(Whh, 2 * HID + hid, HID, 0), Wh21 = LD8(Whh, 2 * HID + hid, HID, 1);
    f16x8 Wh22 = LD8(Whh, 2 * HID + hid, HID, 2), Wh23 = LD8(Whh, 2 * HID + hid, HID, 3);
    f16x8 Wh30 = LD8(Whh, 3 * HID + hid, HID, 0), Wh31 = LD8(Whh, 3 * HID + hid, HID, 1);
    f16x8 Wh32 = LD8(Whh, 3 * HID + hid, HID, 2), Wh33 = LD8(Whh, 3 * HID + hid, HID, 3);
    asm("" : "+a"(Wx00), "+a"(Wx01), "+a"(Wx10), "+a"(Wx11),
             "+a"(Wx20), "+a"(Wx21), "+a"(Wx30), "+a"(Wx31));
    asm("" : "+a"(Wh00), "+a"(Wh01), "+a"(Wh02), "+a"(Wh03),
             "+a"(Wh10), "+a"(Wh11), "+a"(Wh12), "+a"(Wh13));
    asm("" : "+a"(Wh20), "+a"(Wh21), "+a"(Wh22), "+a"(Wh23),
             "+a"(Wh30), "+a"(Wh31), "+a"(Wh32), "+a"(Wh33));

    const float bias0 = bih[0 * HID + hid] + bhh[0 * HID + hid];
    const float bias1 = bih[1 * HID + hid] + bhh[1 * HID + hid];
    const float bias2 = bih[2 * HID + hid] + bhh[2 * HID + hid];
    const float bias3 = bih[3 * HID + hid] + bhh[3 * HID + hid];
    const f32x4 bv0 = {bias0, bias0, bias0, bias0};
    const f32x4 bv1 = {bias1, bias1, bias1, bias1};
    const f32x4 bv2 = {bias2, bias2, bias2, bias2};
    const f32x4 bv3 = {bias3, bias3, bias3, bias3};

    float cc = cstate[(size_t)b * HID + hid];          // all kg duplicates
    float hv = hstate[(size_t)b * HID + hid];
    if (kg == 0) h_lds[0][hid] = (_Float16)hv;

    // x loaders: wave 7 lanes 0..15, coalesced float4, distance-2 prefetch
    const float4* xrow = (const float4*)(x + (size_t)b * TLEN * DIN);
    const int lk = tid - 448;
    const bool ldr = ((unsigned)lk < 16u);
    float4 xpfA = make_float4(0, 0, 0, 0), xpfB = xpfA;
    if (ldr) {
        float4 v = xrow[(size_t)t0 * (DIN / 4) + lk];
        f16x4 pw; pw[0] = (_Float16)v.x; pw[1] = (_Float16)v.y;
        pw[2] = (_Float16)v.z; pw[3] = (_Float16)v.w;
        *(f16x4*)&x_lds[0][lk * 4] = pw;
        int ta = t0 + 1 < TLEN ? t0 + 1 : TLEN - 1;
        int tb = t0 + 2 < TLEN ? t0 + 2 : TLEN - 1;
        xpfA = xrow[(size_t)ta * (DIN / 4) + lk];
        xpfB = xrow[(size_t)tb * (DIN / 4) + lk];
    }
    BARRIER();

#define L0_STEP(T, P, XPF) do {                                                  \
    if (ldr) {                                                                   \
        f16x4 pw; pw[0] = (_Float16)XPF.x; pw[1] = (_Float16)XPF.y;              \
        pw[2] = (_Float16)XPF.z; pw[3] = (_Float16)XPF.w;                        \
        *(f16x4*)&x_lds[(P) ^ 1][lk * 4] = pw;                                   \
        int tn = (T) + 3; if (tn > TLEN - 1) tn = TLEN - 1;                      \
        XPF = xrow[(size_t)tn * (DIN / 4) + lk];                                 \
    }                                                                            \
    f16x8 xa0 = *(const f16x8*)&x_lds[P][kg * 8];                                \
    f16x8 xa1 = *(const f16x8*)&x_lds[P][32 + kg * 8];                           \
    f16x8 ha0 = *(const f16x8*)&h_lds[P][kg * 8];                                \
    f16x8 ha1 = *(const f16x8*)&h_lds[P][32 + kg * 8];                           \
    f16x8 ha2 = *(const f16x8*)&h_lds[P][64 + kg * 8];                           \
    f16x8 ha3 = *(const f16x8*)&h_lds[P][96 + kg * 8];                           \
    f32x4 a0 = MFMA16(xa0, Wx00, bv0);                                           \
    f32x4 a1 = MFMA16(xa0, Wx10, bv1);                                           \
    f32x4 a2 = MFMA16(xa0, Wx20, bv2);                                           \
    f32x4 a3 = MFMA16(xa0, Wx30, bv3);                                           \
    a0 = MFMA16(xa1, Wx01, a0); a1 = MFMA16(xa1, Wx11, a1);                      \
    a2 = MFMA16(xa1, Wx21, a2); a3 = MFMA16(xa1, Wx31, a3);                      \
    a0 = MFMA16(ha0, Wh00, a0); a1 = MFMA16(ha0, Wh10, a1);                      \
    a2 = MFMA16(ha0, Wh20, a2); a3 = MFMA16(ha0, Wh30, a3);                      \
    a0 = MFMA16(ha1, Wh01, a0); a1 = MFMA16(ha1, Wh11, a1);                      \
    a2 = MFMA16(ha1, Wh21, a2); a3 = MFMA16(ha1, Wh31, a3);                      \
    a0 = MFMA16(ha2, Wh02, a0); a1 = MFMA16(ha2, Wh12, a1);                      \
    a2 = MFMA16(ha2, Wh22, a2); a3 = MFMA16(ha2, Wh32, a3);                      \
    a0 = MFMA16(ha3, Wh03, a0); a1 = MFMA16(ha3, Wh13, a1);                      \
    a2 = MFMA16(ha3, Wh23, a2); a3 = MFMA16(ha3, Wh33, a3);                      \
    float iv = sig_(a0[0]), fv = sig_(a1[0]);                                    \
    float gv = tanh_(a2[0]), ov = sig_(a3[0]);                                   \
    cc = fmaf(fv, cc, iv * gv);                                                  \
    hv = ov * tanh_(cc);                                                         \
    _Float16 hh = (_Float16)hv;                                                  \
    if (kg == 0) {                                                               \
        h_lds[(P) ^ 1][hid] = hh;                                                \
        y0[((size_t)((T) - t0) * BATCH + b) * HID + hid] = hh;                   \
    }                                                                            \
    BARRIER();                                                                   \
} while (0)

    const int nt = t1 - t0;                            // even by construction
    for (int s = 0; s + 1 < nt; s += 2) {
        L0_STEP(t0 + s,     0, xpfA);
        L0_STEP(t0 + s + 1, 1, xpfB);
    }
#undef L0_STEP

    if (kg == 0) {
        cstate[(size_t)b * HID + hid] = cc;
        hstate[(size_t)b * HID + hid] = hv;
    }
}

// ===================== Layer 1 =====================
__global__ void __attribute__((amdgpu_flat_work_group_size(512, 512), amdgpu_waves_per_eu(2, 2)))
lstm_l1(const _Float16* __restrict__ y0in,
        const float* __restrict__ Wih, const float* __restrict__ Whh,
        const float* __restrict__ bih, const float* __restrict__ bhh,
        float* __restrict__ hstate, float* __restrict__ cstate,
        int t0, int t1)
{
    const int b    = blockIdx.x;
    const int tid  = threadIdx.x;
    const int lane = tid & 63, wave = tid >> 6;
    const int col  = lane & 15, kg = lane >> 4;
    const int hid  = wave * 16 + col;

    __shared__ __align__(16) _Float16 y_lds[2][HID];
    __shared__ __align__(16) _Float16 h_lds[2][HID];

    f16x8 Wy00 = LD8(Wih, 0 * HID + hid, HID, 0), Wy01 = LD8(Wih, 0 * HID + hid, HID, 1);
    f16x8 Wy02 = LD8(Wih, 0 * HID + hid, HID, 2), Wy03 = LD8(Wih, 0 * HID + hid, HID, 3);
    f16x8 Wy10 = LD8(Wih, 1 * HID + hid, HID, 0), Wy11 = LD8(Wih, 1 * HID + hid, HID, 1);
    f16x8 Wy12 = LD8(Wih, 1 * HID + hid, HID, 2), Wy13 = LD8(Wih, 1 * HID + hid, HID, 3);
    f16x8 Wy20 = LD8(Wih, 2 * HID + hid, HID, 0), Wy21 = LD8(Wih, 2 * HID + hid, HID, 1);
    f16x8 Wy22 = LD8(Wih, 2 * HID + hid, HID, 2), Wy23 = LD8(Wih, 2 * HID + hid, HID, 3);
    f16x8 Wy30 = LD8(Wih, 3 * HID + hid, HID, 0), Wy31 = LD8(Wih, 3 * HID + hid, HID, 1);
    f16x8 Wy32 = LD8(Wih, 3 * HID + hid, HID, 2), Wy33 = LD8(Wih, 3 * HID + hid, HID, 3);
    f16x8 Wh00 = LD8(Whh, 0 * HID + hid, HID, 0), Wh01 = LD8(Whh, 0 * HID + hid, HID, 1);
    f16x8 Wh02 = LD8(Whh, 0 * HID + hid, HID, 2), Wh03 = LD8(Whh, 0 * HID + hid, HID, 3);
    f16x8 Wh10 = LD8(Whh, 1 * HID + hid, HID, 0), Wh11 = LD8(Whh, 1 * HID + hid, HID, 1);
    f16x8 Wh12 = LD8(Whh, 1 * HID + hid, HID, 2), Wh13 = LD8(Whh, 1 * HID + hid, HID, 3);
    f16x8 Wh20 = LD8(Whh, 2 * HID + hid, HID, 0), Wh21 = LD8(Whh, 2 * HID + hid, HID, 1);
    f16x8 Wh22 = LD8(Whh, 2 * HID + hid, HID, 2), Wh23 = LD8(Whh, 2 * HID + hid, HID, 3);
    f16x8 Wh30 = LD8(Whh, 3 * HID + hid, HID, 0), Wh31 = LD8(Whh, 3 * HID + hid, HID, 1);
    f16x8 Wh32 = LD8(Whh, 3 * HID + hid, HID, 2), Wh33 = LD8(Whh, 3 * HID + hid, HID, 3);
    asm("" : "+a"(Wy00), "+a"(Wy01), "+a"(Wy02), "+a"(Wy03),
             "+a"(Wy10), "+a"(Wy11), "+a"(Wy12), "+a"(Wy13));
    asm("" : "+a"(Wy20), "+a"(Wy21), "+a"(Wy22), "+a"(Wy23),
             "+a"(Wy30), "+a"(Wy31), "+a"(Wy32), "+a"(Wy33));
    asm("" : "+a"(Wh00), "+a"(Wh01), "+a"(Wh02), "+a"(Wh03),
             "+a"(Wh10), "+a"(Wh11), "+a"(Wh12), "+a"(Wh13));
    asm("" : "+a"(Wh20), "+a"(Wh21), "+a"(Wh22), "+a"(Wh23),
             "+a"(Wh30), "+a"(Wh31), "+a"(Wh32), "+a"(Wh33));

    const float bias0 = bih[0 * HID + hid] + bhh[0 * HID + hid];
    const float bias1 = bih[1 * HID + hid] + bhh[1 * HID + hid];
    const float bias2 = bih[2 * HID + hid] + bhh[2 * HID + hid];
    const float bias3 = bih[3 * HID + hid] + bhh[3 * HID + hid];
    const f32x4 bv0 = {bias0, bias0, bias0, bias0};
    const f32x4 bv1 = {bias1, bias1, bias1, bias1};
    const f32x4 bv2 = {bias2, bias2, bias2, bias2};
    const f32x4 bv3 = {bias3, bias3, bias3, bias3};

    float cc = cstate[(size_t)b * HID + hid];
    float hv = hstate[(size_t)b * HID + hid];
    if (kg == 0) h_lds[0][hid] = (_Float16)hv;

    const uint4* yrow = (const uint4*)(y0in);
    const int lk = tid - 448;
    const bool ldr = ((unsigned)lk < 16u);
    const int nt = t1 - t0;
    uint4 ypfA = make_uint4(0, 0, 0, 0), ypfB = ypfA;
    if (ldr) {
        *(uint4*)&y_lds[0][lk * 8] = yrow[((size_t)0 * BATCH + b) * (HID / 8) + lk];
        int ra = 1 < nt - 1 ? 1 : nt - 1;
        int rb = 2 < nt - 1 ? 2 : nt - 1;
        ypfA = yrow[((size_t)ra * BATCH + b) * (HID / 8) + lk];
        ypfB = yrow[((size_t)rb * BATCH + b) * (HID / 8) + lk];
    }
    BARRIER();

#define L1_STEP(REL, P, YPF) do {                                                \
    if (ldr) {                                                                   \
        *(uint4*)&y_lds[(P) ^ 1][lk * 8] = YPF;                                  \
        int rn = (REL) + 3; if (rn > nt - 1) rn = nt - 1;                        \
        YPF = yrow[((size_t)rn * BATCH + b) * (HID / 8) + lk];                   \
    }                                                                            \
    f16x8 ya0 = *(const f16x8*)&y_lds[P][kg * 8];                                \
    f16x8 ya1 = *(const f16x8*)&y_lds[P][32 + kg * 8];                           \
    f16x8 ya2 = *(const f16x8*)&y_lds[P][64 + kg * 8];                           \
    f16x8 ya3 = *(const f16x8*)&y_lds[P][96 + kg * 8];                           \
    f16x8 ha0 = *(const f16x8*)&h_lds[P][kg * 8];                                \
    f16x8 ha1 = *(const f16x8*)&h_lds[P][32 + kg * 8];                           \
    f16x8 ha2 = *(const f16x8*)&h_lds[P][64 + kg * 8];                           \
    f16x8 ha3 = *(const f16x8*)&h_lds[P][96 + kg * 8];                           \
    f32x4 a0 = MFMA16(ya0, Wy00, bv0);                                           \
    f32x4 a1 = MFMA16(ya0, Wy10, bv1);                                           \
    f32x4 a2 = MFMA16(ya0, Wy20, bv2);                                           \
    f32x4 a3 = MFMA16(ya0, Wy30, bv3);                                           \
    a0 = MFMA16(ya1, Wy01, a0); a1 = MFMA16(ya1, Wy11, a1);                      \
    a2 = MFMA16(ya1, Wy21, a2); a3 = MFMA16(ya1, Wy31, a3);                      \
    a0 = MFMA16(ya2, Wy02, a0); a1 = MFMA16(ya2, Wy12, a1);                      \
    a2 = MFMA16(ya2, Wy22, a2); a3 = MFMA16(ya2, Wy32, a3);                      \
    a0 = MFMA16(ya3, Wy03, a0); a1 = MFMA16(ya3, Wy13, a1);                      \
    a2 = MFMA16(ya3, Wy23, a2); a3 = MFMA16(ya3, Wy33, a3);                      \
    a0 = MFMA16(ha0, Wh00, a0); a1 = MFMA16(ha0, Wh10, a1);                      \
    a2 = MFMA16(ha0, Wh20, a2); a3 = MFMA16(ha0, Wh30, a3);                      \
    a0 = MFMA16(ha1, Wh01, a0); a1 = MFMA16(ha1, Wh11, a1);                      \
    a2 = MFMA16(ha1, Wh21, a2); a3 = MFMA16(ha1, Wh31, a3);                      \
    a0 = MFMA16(ha2, Wh02, a0); a1 = MFMA16(ha2, Wh12, a1);                      \
    a2 = MFMA16(ha2, Wh22, a2); a3 = MFMA16(ha2, Wh32, a3);                      \
    a0 = MFMA16(ha3, Wh03, a0); a1 = MFMA16(ha3, Wh13, a1);                      \
    a2 = MFMA16(ha3, Wh23, a2); a3 = MFMA16(ha3, Wh33, a3);                      \
    float iv = sig_(a0[0]), fv = sig_(a1[0]);                                    \
    float gv = tanh_(a2[0]), ov = sig_(a3[0]);                                   \
    cc = fmaf(fv, cc, iv * gv);                                                  \
    hv = ov * tanh_(cc);                                                         \
    if (kg == 0) h_lds[(P) ^ 1][hid] = (_Float16)hv;                             \
    BARRIER();                                                                   \
} while (0)

    for (int s = 0; s + 1 < nt; s += 2) {
        L1_STEP(s,     0, ypfA);
        L1_STEP(s + 1, 1, ypfB);
    }
#undef L1_STEP

    if (kg == 0) {
        cstate[(size_t)b * HID + hid] = cc;
        hstate[(size_t)b * HID + hid] = hv;   // final h1 (fc reads this)
    }
}

// ===================== Final FC =====================
__global__ __launch_bounds__(128) void fc_kernel(
    const float* __restrict__ h1, const float* __restrict__ Wfc,
    const float* __restrict__ bfc, float* __restrict__ out)
{
    const int b = blockIdx.x;
    const int o = threadIdx.x;
    __shared__ float hs[HID];
    hs[o] = h1[(size_t)b * HID + o];
    __syncthreads();
    if (o < NOUT) {
        const float4* w  = reinterpret_cast<const float4*>(Wfc + (size_t)o * HID);
        const float4* hv = reinterpret_cast<const float4*>(hs);
        float acc = bfc[o];
        #pragma unroll
        for (int q = 0; q < HID / 4; ++q) {
            float4 wv = w[q]; float4 h4 = hv[q];
            acc = fmaf(wv.x, h4.x, fmaf(wv.y, h4.y, fmaf(wv.z, h4.z, fmaf(wv.w, h4.w, acc))));
        }
        out[(size_t)b * NOUT + o] = acc;
    }
}

extern "C" void kernel_launch(void* const* d_in, const int* in_sizes, int n_in,
                              void* d_out, int out_size, void* d_ws, size_t ws_size,
                              hipStream_t stream) {
    const float* x    = (const float*)d_in[0];
    const float* Wih0 = (const float*)d_in[1];
    const float* Whh0 = (const float*)d_in[2];
    const float* bih0 = (const float*)d_in[3];
    const float* bhh0 = (const float*)d_in[4];
    const float* Wih1 = (const float*)d_in[5];
    const float* Whh1 = (const float*)d_in[6];
    const float* bih1 = (const float*)d_in[7];
    const float* bhh1 = (const float*)d_in[8];
    const float* Wfc  = (const float*)d_in[9];
    const float* bfc  = (const float*)d_in[10];
    float* out = (float*)d_out;

    // ws: hst0 | cst0 | hst1 | cst1 (f32, 128KB each) then y0 slab (f16)
    float* hst0 = (float*)d_ws;
    float* cst0 = hst0 + BATCH * HID;
    float* hst1 = cst0 + BATCH * HID;
    float* cst1 = hst1 + BATCH * HID;
    _Float16* y0 = (_Float16*)(cst1 + BATCH * HID);

    const size_t stateBytes = (size_t)4 * BATCH * HID * sizeof(float);   // 512 KB
    size_t avail = ws_size > stateBytes ? ws_size - stateBytes : 0;
    int Tc = (int)(avail / ((size_t)BATCH * HID * 2));
    if (Tc > TLEN) Tc = TLEN;
    Tc &= ~1;
    if (Tc < 2) Tc = 2;

    hipMemsetAsync(d_ws, 0, stateBytes, stream);

    for (int t0 = 0; t0 < TLEN; t0 += Tc) {
        int t1 = t0 + Tc; if (t1 > TLEN) t1 = TLEN;
        lstm_l0<<<BATCH, 512, 0, stream>>>(x, Wih0, Whh0, bih0, bhh0, hst0, cst0, y0, t0, t1);
        lstm_l1<<<BATCH, 512, 0, stream>>>(y0, Wih1, Whh1, bih1, bhh1, hst1, cst1, t0, t1);
    }
    fc_kernel<<<BATCH, 128, 0, stream>>>(hst1, Wfc, bfc, out);
}

// Round 7
// 650.802 us; speedup vs baseline: 2.0271x; 1.0077x over previous
//
#include <hip/hip_runtime.h>

#define BATCH 256
#define TLEN  512
#define DIN   64
#define HID   128
#define NOUT  40

typedef _Float16 f16x8 __attribute__((ext_vector_type(8)));
typedef _Float16 f16x4 __attribute__((ext_vector_type(4)));
typedef float    f32x4 __attribute__((ext_vector_type(4)));

#define MFMA16(a, b, c) __builtin_amdgcn_mfma_f32_16x16x32_f16((a), (b), (c), 0, 0, 0)

// LDS-visibility barrier only: no vmcnt drain.
#define BARRIER() do {                                      \
    asm volatile("s_waitcnt lgkmcnt(0)" ::: "memory");      \
    __builtin_amdgcn_s_barrier();                           \
} while (0)

static __device__ __forceinline__ f16x8 pack8(float4 a, float4 b) {
    f16x8 v;
    v[0] = (_Float16)a.x; v[1] = (_Float16)a.y; v[2] = (_Float16)a.z; v[3] = (_Float16)a.w;
    v[4] = (_Float16)b.x; v[5] = (_Float16)b.y; v[6] = (_Float16)b.z; v[7] = (_Float16)b.w;
    return v;
}
static __device__ __forceinline__ float sig_(float x) {
    return __builtin_amdgcn_rcpf(1.0f + __expf(-x));
}
static __device__ __forceinline__ float tanh_(float x) {
    return fmaf(-2.0f, __builtin_amdgcn_rcpf(__expf(2.0f * x) + 1.0f), 1.0f);
}

// Weight fragment loader; uses kernel-local `kg`. k = kt*32 + kg*8 + j.
#define LD8(base, g, K, kt) pack8(*(const float4*)((base) + (size_t)(g) * (K) + (kt) * 32 + kg * 8), \
                                  *(const float4*)((base) + (size_t)(g) * (K) + (kt) * 32 + kg * 8 + 4))

// ===================== Layer 0 =====================
// 256 blocks x 512 thr (8 waves). Wave w owns hid [w*16,w*16+16), all 4 gates.
// Pipelined: x-projection for step t+1 computed during step t (xacc in U/V);
// h-chain is only 4 dependent MFMAs with C-init = xacc[t].
__global__ void __attribute__((amdgpu_flat_work_group_size(512, 512), amdgpu_waves_per_eu(2, 2)))
lstm_l0(const float* __restrict__ x,
        const float* __restrict__ Wih, const float* __restrict__ Whh,
        const float* __restrict__ bih, const float* __restrict__ bhh,
        float* __restrict__ hstate, float* __restrict__ cstate,
        _Float16* __restrict__ y0, int t0, int t1)
{
    const int b    = blockIdx.x;
    const int tid  = threadIdx.x;
    const int lane = tid & 63, wave = tid >> 6;
    const int col  = lane & 15, kg = lane >> 4;
    const int hid  = wave * 16 + col;

    __shared__ __align__(16) _Float16 x_lds[2][DIN];
    __shared__ __align__(16) _Float16 h_lds[2][HID];

    // ---- weight fragments -> AGPR-pinned ----
    f16x8 Wx00 = LD8(Wih, 0 * HID + hid, DIN, 0), Wx01 = LD8(Wih, 0 * HID + hid, DIN, 1);
    f16x8 Wx10 = LD8(Wih, 1 * HID + hid, DIN, 0), Wx11 = LD8(Wih, 1 * HID + hid, DIN, 1);
    f16x8 Wx20 = LD8(Wih, 2 * HID + hid, DIN, 0), Wx21 = LD8(Wih, 2 * HID + hid, DIN, 1);
    f16x8 Wx30 = LD8(Wih, 3 * HID + hid, DIN, 0), Wx31 = LD8(Wih, 3 * HID + hid, DIN, 1);
    f16x8 Wh00 = LD8(Whh, 0 * HID + hid, HID, 0), Wh01 = LD8(Whh, 0 * HID + hid, HID, 1);
    f16x8 Wh02 = LD8(Whh, 0 * HID + hid, HID, 2), Wh03 = LD8(Whh, 0 * HID + hid, HID, 3);
    f16x8 Wh10 = LD8(Whh, 1 * HID + hid, HID, 0), Wh11 = LD8(Whh, 1 * HID + hid, HID, 1);
    f16x8 Wh12 = LD8(Whh, 1 * HID + hid, HID, 2), Wh13 = LD8(Whh, 1 * HID + hid, HID, 3);
    f16x8 Wh20 = LD8(Whh, 2 * HID + hid, HID, 0), Wh21 = LD8(Whh, 2 * HID + hid, HID, 1);
    f16x8 Wh22 = LD8(Whh, 2 * HID + hid, HID, 2), Wh23 = LD8(Whh, 2 * HID + hid, HID, 3);
    f16x8 Wh30 = LD8(Whh, 3 * HID + hid, HID, 0), Wh31 = LD8(Whh, 3 * HID + hid, HID, 1);
    f16x8 Wh32 = LD8(Whh, 3 * HID + hid, HID, 2), Wh33 = LD8(Whh, 3 * HID + hid, HID, 3);
    asm("" : "+a"(Wx00), "+a"(Wx01), "+a"(Wx10), "+a"(Wx11),
             "+a"(Wx20), "+a"(Wx21), "+a"(Wx30), "+a"(Wx31));
    asm("" : "+a"(Wh00), "+a"(Wh01), "+a"(Wh02), "+a"(Wh03),
             "+a"(Wh10), "+a"(Wh11), "+a"(Wh12), "+a"(Wh13));
    asm("" : "+a"(Wh20), "+a"(Wh21), "+a"(Wh22), "+a"(Wh23),
             "+a"(Wh30), "+a"(Wh31), "+a"(Wh32), "+a"(Wh33));

    const float bs0 = bih[0 * HID + hid] + bhh[0 * HID + hid];
    const float bs1 = bih[1 * HID + hid] + bhh[1 * HID + hid];
    const float bs2 = bih[2 * HID + hid] + bhh[2 * HID + hid];
    const float bs3 = bih[3 * HID + hid] + bhh[3 * HID + hid];
    const f32x4 z4 = {0.f, 0.f, 0.f, 0.f};

    float cc = cstate[(size_t)b * HID + hid];
    float hv = hstate[(size_t)b * HID + hid];
    if (kg == 0) h_lds[0][hid] = (_Float16)hv;

    // x loaders: wave 7 lanes 0..15, one float4 each (cvt to f16 at LDS write)
    const float4* xrow = (const float4*)(x + (size_t)b * TLEN * DIN);
    const int lk = tid - 448;
    const bool ldr = ((unsigned)lk < 16u);
    float4 xpfA = make_float4(0, 0, 0, 0), xpfB = xpfA;
    if (ldr) {
        int g0 = t0,     g1 = t0 + 1, g2 = t0 + 2, g3 = t0 + 3;
        if (g1 > TLEN - 1) g1 = TLEN - 1;
        if (g2 > TLEN - 1) g2 = TLEN - 1;
        if (g3 > TLEN - 1) g3 = TLEN - 1;
        float4 v0 = xrow[(size_t)g0 * (DIN / 4) + lk];
        float4 v1 = xrow[(size_t)g1 * (DIN / 4) + lk];
        f16x4 p;
        p[0] = (_Float16)v0.x; p[1] = (_Float16)v0.y; p[2] = (_Float16)v0.z; p[3] = (_Float16)v0.w;
        *(f16x4*)&x_lds[0][lk * 4] = p;
        p[0] = (_Float16)v1.x; p[1] = (_Float16)v1.y; p[2] = (_Float16)v1.z; p[3] = (_Float16)v1.w;
        *(f16x4*)&x_lds[1][lk * 4] = p;
        xpfA = xrow[(size_t)g2 * (DIN / 4) + lk];
        xpfB = xrow[(size_t)g3 * (DIN / 4) + lk];
    }
    BARRIER();

    // xacc[t0] from x_lds[0]
    f32x4 U0, U1, U2, U3, V0, V1, V2, V3;
    {
        f16x8 p0 = *(const f16x8*)&x_lds[0][kg * 8];
        f16x8 p1 = *(const f16x8*)&x_lds[0][32 + kg * 8];
        U0 = MFMA16(p0, Wx00, z4); U1 = MFMA16(p0, Wx10, z4);
        U2 = MFMA16(p0, Wx20, z4); U3 = MFMA16(p0, Wx30, z4);
        U0 = MFMA16(p1, Wx01, U0); U1 = MFMA16(p1, Wx11, U1);
        U2 = MFMA16(p1, Wx21, U2); U3 = MFMA16(p1, Wx31, U3);
    }
    BARRIER();   // protect x_lds[0] from step-0 loader overwrite

#define L0_STEP(T, P, XPF, C0, C1, C2, C3, N0, N1, N2, N3) do {                  \
    if (ldr) {                                                                   \
        f16x4 pw; pw[0] = (_Float16)XPF.x; pw[1] = (_Float16)XPF.y;              \
        pw[2] = (_Float16)XPF.z; pw[3] = (_Float16)XPF.w;                        \
        *(f16x4*)&x_lds[P][lk * 4] = pw;                                         \
        int tn = (T) + 4; if (tn > TLEN - 1) tn = TLEN - 1;                      \
        XPF = xrow[(size_t)tn * (DIN / 4) + lk];                                 \
    }                                                                            \
    f16x8 ha0 = *(const f16x8*)&h_lds[P][kg * 8];                                \
    f16x8 ha1 = *(const f16x8*)&h_lds[P][32 + kg * 8];                           \
    f16x8 ha2 = *(const f16x8*)&h_lds[P][64 + kg * 8];                           \
    f16x8 ha3 = *(const f16x8*)&h_lds[P][96 + kg * 8];                           \
    f16x8 xa0 = *(const f16x8*)&x_lds[(P) ^ 1][kg * 8];                          \
    f16x8 xa1 = *(const f16x8*)&x_lds[(P) ^ 1][32 + kg * 8];                     \
    f32x4 a0 = MFMA16(ha0, Wh00, C0), a1 = MFMA16(ha0, Wh10, C1);                \
    f32x4 a2 = MFMA16(ha0, Wh20, C2), a3 = MFMA16(ha0, Wh30, C3);                \
    a0 = MFMA16(ha1, Wh01, a0); a1 = MFMA16(ha1, Wh11, a1);                      \
    a2 = MFMA16(ha1, Wh21, a2); a3 = MFMA16(ha1, Wh31, a3);                      \
    a0 = MFMA16(ha2, Wh02, a0); a1 = MFMA16(ha2, Wh12, a1);                      \
    a2 = MFMA16(ha2, Wh22, a2); a3 = MFMA16(ha2, Wh32, a3);                      \
    a0 = MFMA16(ha3, Wh03, a0); a1 = MFMA16(ha3, Wh13, a1);                      \
    a2 = MFMA16(ha3, Wh23, a2); a3 = MFMA16(ha3, Wh33, a3);                      \
    N0 = MFMA16(xa0, Wx00, z4); N1 = MFMA16(xa0, Wx10, z4);                      \
    N2 = MFMA16(xa0, Wx20, z4); N3 = MFMA16(xa0, Wx30, z4);                      \
    N0 = MFMA16(xa1, Wx01, N0); N1 = MFMA16(xa1, Wx11, N1);                      \
    N2 = MFMA16(xa1, Wx21, N2); N3 = MFMA16(xa1, Wx31, N3);                      \
    float iv = sig_(a0[0] + bs0), fv = sig_(a1[0] + bs1);                        \
    float gv = tanh_(a2[0] + bs2), ov = sig_(a3[0] + bs3);                       \
    cc = fmaf(fv, cc, iv * gv);                                                  \
    hv = ov * tanh_(cc);                                                         \
    _Float16 hh = (_Float16)hv;                                                  \
    if (kg == 0) {                                                               \
        h_lds[(P) ^ 1][hid] = hh;                                                \
        y0[((size_t)((T) - t0) * BATCH + b) * HID + hid] = hh;                   \
    }                                                                            \
    BARRIER();                                                                   \
} while (0)

    const int nt = t1 - t0;                            // even by construction
    for (int s = 0; s + 1 < nt; s += 2) {
        L0_STEP(t0 + s,     0, xpfA, U0, U1, U2, U3, V0, V1, V2, V3);
        L0_STEP(t0 + s + 1, 1, xpfB, V0, V1, V2, V3, U0, U1, U2, U3);
    }
#undef L0_STEP

    if (kg == 0) {
        cstate[(size_t)b * HID + hid] = cc;
        hstate[(size_t)b * HID + hid] = hv;
    }
}

// ===================== Layer 1 =====================
__global__ void __attribute__((amdgpu_flat_work_group_size(512, 512), amdgpu_waves_per_eu(2, 2)))
lstm_l1(const _Float16* __restrict__ y0in,
        const float* __restrict__ Wih, const float* __restrict__ Whh,
        const float* __restrict__ bih, const float* __restrict__ bhh,
        float* __restrict__ hstate, float* __restrict__ cstate,
        int t0, int t1)
{
    const int b    = blockIdx.x;
    const int tid  = threadIdx.x;
    const int lane = tid & 63, wave = tid >> 6;
    const int col  = lane & 15, kg = lane >> 4;
    const int hid  = wave * 16 + col;

    __shared__ __align__(16) _Float16 y_lds[2][HID];
    __shared__ __align__(16) _Float16 h_lds[2][HID];

    f16x8 Wy00 = LD8(Wih, 0 * HID + hid, HID, 0), Wy01 = LD8(Wih, 0 * HID + hid, HID, 1);
    f16x8 Wy02 = LD8(Wih, 0 * HID + hid, HID, 2), Wy03 = LD8(Wih, 0 * HID + hid, HID, 3);
    f16x8 Wy10 = LD8(Wih, 1 * HID + hid, HID, 0), Wy11 = LD8(Wih, 1 * HID + hid, HID, 1);
    f16x8 Wy12 = LD8(Wih, 1 * HID + hid, HID, 2), Wy13 = LD8(Wih, 1 * HID + hid, HID, 3);
    f16x8 Wy20 = LD8(Wih, 2 * HID + hid, HID, 0), Wy21 = LD8(Wih, 2 * HID + hid, HID, 1);
    f16x8 Wy22 = LD8(Wih, 2 * HID + hid, HID, 2), Wy23 = LD8(Wih, 2 * HID + hid, HID, 3);
    f16x8 Wy30 = LD8(Wih, 3 * HID + hid, HID, 0), Wy31 = LD8(Wih, 3 * HID + hid, HID, 1);
    f16x8 Wy32 = LD8(Wih, 3 * HID + hid, HID, 2), Wy33 = LD8(Wih, 3 * HID + hid, HID, 3);
    f16x8 Wh00 = LD8(Whh, 0 * HID + hid, HID, 0), Wh01 = LD8(Whh, 0 * HID + hid, HID, 1);
    f16x8 Wh02 = LD8(Whh, 0 * HID + hid, HID, 2), Wh03 = LD8(Whh, 0 * HID + hid, HID, 3);
    f16x8 Wh10 = LD8(Whh, 1 * HID + hid, HID, 0), Wh11 = LD8(Whh, 1 * HID + hid, HID, 1);
    f16x8 Wh12 = LD8(Whh, 1 * HID + hid, HID, 2), Wh13 = LD8(Whh, 1 * HID + hid, HID, 3);
    f16x8 Wh20 = LD8(Whh, 2 * HID + hid, HID, 0), Wh21 = LD8(Whh, 2 * HID + hid, HID, 1);
    f16x8 Wh22 = LD8(Whh, 2 * HID + hid, HID, 2), Wh23 = LD8(Whh, 2 * HID + hid, HID, 3);
    f16x8 Wh30 = LD8(Whh, 3 * HID + hid, HID, 0), Wh31 = LD8(Whh, 3 * HID + hid, HID, 1);
    f16x8 Wh32 = LD8(Whh, 3 * HID + hid, HID, 2), Wh33 = LD8(Whh, 3 * HID + hid, HID, 3);
    asm("" : "+a"(Wy00), "+a"(Wy01), "+a"(Wy02), "+a"(Wy03),
             "+a"(Wy10), "+a"(Wy11), "+a"(Wy12), "+a"(Wy13));
    asm("" : "+a"(Wy20), "+a"(Wy21), "+a"(Wy22), "+a"(Wy23),
             "+a"(Wy30), "+a"(Wy31), "+a"(Wy32), "+a"(Wy33));
    asm("" : "+a"(Wh00), "+a"(Wh01), "+a"(Wh02), "+a"(Wh03),
             "+a"(Wh10), "+a"(Wh11), "+a"(Wh12), "+a"(Wh13));
    asm("" : "+a"(Wh20), "+a"(Wh21), "+a"(Wh22), "+a"(Wh23),
             "+a"(Wh30), "+a"(Wh31), "+a"(Wh32), "+a"(Wh33));

    const float bs0 = bih[0 * HID + hid] + bhh[0 * HID + hid];
    const float bs1 = bih[1 * HID + hid] + bhh[1 * HID + hid];
    const float bs2 = bih[2 * HID + hid] + bhh[2 * HID + hid];
    const float bs3 = bih[3 * HID + hid] + bhh[3 * HID + hid];
    const f32x4 z4 = {0.f, 0.f, 0.f, 0.f};

    float cc = cstate[(size_t)b * HID + hid];
    float hv = hstate[(size_t)b * HID + hid];
    if (kg == 0) h_lds[0][hid] = (_Float16)hv;

    const uint4* yrow = (const uint4*)(y0in);
    const int lk = tid - 448;
    const bool ldr = ((unsigned)lk < 16u);
    const int nt = t1 - t0;
    uint4 ypfA = make_uint4(0, 0, 0, 0), ypfB = ypfA;
    if (ldr) {
        int i1 = 1 < nt - 1 ? 1 : nt - 1;
        int i2 = 2 < nt - 1 ? 2 : nt - 1;
        int i3 = 3 < nt - 1 ? 3 : nt - 1;
        *(uint4*)&y_lds[0][lk * 8] = yrow[((size_t)0 * BATCH + b) * (HID / 8) + lk];
        *(uint4*)&y_lds[1][lk * 8] = yrow[((size_t)i1 * BATCH + b) * (HID / 8) + lk];
        ypfA = yrow[((size_t)i2 * BATCH + b) * (HID / 8) + lk];
        ypfB = yrow[((size_t)i3 * BATCH + b) * (HID / 8) + lk];
    }
    BARRIER();

    // yacc[0] from y_lds[0]
    f32x4 U0, U1, U2, U3, V0, V1, V2, V3;
    {
        f16x8 p0 = *(const f16x8*)&y_lds[0][kg * 8];
        f16x8 p1 = *(const f16x8*)&y_lds[0][32 + kg * 8];
        f16x8 p2 = *(const f16x8*)&y_lds[0][64 + kg * 8];
        f16x8 p3 = *(const f16x8*)&y_lds[0][96 + kg * 8];
        U0 = MFMA16(p0, Wy00, z4); U1 = MFMA16(p0, Wy10, z4);
        U2 = MFMA16(p0, Wy20, z4); U3 = MFMA16(p0, Wy30, z4);
        U0 = MFMA16(p1, Wy01, U0); U1 = MFMA16(p1, Wy11, U1);
        U2 = MFMA16(p1, Wy21, U2); U3 = MFMA16(p1, Wy31, U3);
        U0 = MFMA16(p2, Wy02, U0); U1 = MFMA16(p2, Wy12, U1);
        U2 = MFMA16(p2, Wy22, U2); U3 = MFMA16(p2, Wy32, U3);
        U0 = MFMA16(p3, Wy03, U0); U1 = MFMA16(p3, Wy13, U1);
        U2 = MFMA16(p3, Wy23, U2); U3 = MFMA16(p3, Wy33, U3);
    }
    BARRIER();   // protect y_lds[0] from step-0 loader overwrite

#define L1_STEP(REL, P, YPF, C0, C1, C2, C3, N0, N1, N2, N3) do {                \
    if (ldr) {                                                                   \
        *(uint4*)&y_lds[P][lk * 8] = YPF;                                        \
        int rn = (REL) + 4; if (rn > nt - 1) rn = nt - 1;                        \
        YPF = yrow[((size_t)rn * BATCH + b) * (HID / 8) + lk];                   \
    }                                                                            \
    f16x8 ha0 = *(const f16x8*)&h_lds[P][kg * 8];                                \
    f16x8 ha1 = *(const f16x8*)&h_lds[P][32 + kg * 8];                           \
    f16x8 ha2 = *(const f16x8*)&h_lds[P][64 + kg * 8];                           \
    f16x8 ha3 = *(const f16x8*)&h_lds[P][96 + kg * 8];                           \
    f16x8 ya0 = *(const f16x8*)&y_lds[(P) ^ 1][kg * 8];                          \
    f16x8 ya1 = *(const f16x8*)&y_lds[(P) ^ 1][32 + kg * 8];                     \
    f16x8 ya2 = *(const f16x8*)&y_lds[(P) ^ 1][64 + kg * 8];                     \
    f16x8 ya3 = *(const f16x8*)&y_lds[(P) ^ 1][96 + kg * 8];                     \
    f32x4 a0 = MFMA16(ha0, Wh00, C0), a1 = MFMA16(ha0, Wh10, C1);                \
    f32x4 a2 = MFMA16(ha0, Wh20, C2), a3 = MFMA16(ha0, Wh30, C3);                \
    a0 = MFMA16(ha1, Wh01, a0); a1 = MFMA16(ha1, Wh11, a1);                      \
    a2 = MFMA16(ha1, Wh21, a2); a3 = MFMA16(ha1, Wh31, a3);                      \
    a0 = MFMA16(ha2, Wh02, a0); a1 = MFMA16(ha2, Wh12, a1);                      \
    a2 = MFMA16(ha2, Wh22, a2); a3 = MFMA16(ha2, Wh32, a3);                      \
    a0 = MFMA16(ha3, Wh03, a0); a1 = MFMA16(ha3, Wh13, a1);                      \
    a2 = MFMA16(ha3, Wh23, a2); a3 = MFMA16(ha3, Wh33, a3);                      \
    N0 = MFMA16(ya0, Wy00, z4); N1 = MFMA16(ya0, Wy10, z4);                      \
    N2 = MFMA16(ya0, Wy20, z4); N3 = MFMA16(ya0, Wy30, z4);                      \
    N0 = MFMA16(ya1, Wy01, N0); N1 = MFMA16(ya1, Wy11, N1);                      \
    N2 = MFMA16(ya1, Wy21, N2); N3 = MFMA16(ya1, Wy31, N3);                      \
    N0 = MFMA16(ya2, Wy02, N0); N1 = MFMA16(ya2, Wy12, N1);                      \
    N2 = MFMA16(ya2, Wy22, N2); N3 = MFMA16(ya2, Wy32, N3);                      \
    N0 = MFMA16(ya3, Wy03, N0); N1 = MFMA16(ya3, Wy13, N1);                      \
    N2 = MFMA16(ya3, Wy23, N2); N3 = MFMA16(ya3, Wy33, N3);                      \
    float iv = sig_(a0[0] + bs0), fv = sig_(a1[0] + bs1);                        \
    float gv = tanh_(a2[0] + bs2), ov = sig_(a3[0] + bs3);                       \
    cc = fmaf(fv, cc, iv * gv);                                                  \
    hv = ov * tanh_(cc);                                                         \
    if (kg == 0) h_lds[(P) ^ 1][hid] = (_Float16)hv;                             \
    BARRIER();                                                                   \
} while (0)

    for (int s = 0; s + 1 < nt; s += 2) {
        L1_STEP(s,     0, ypfA, U0, U1, U2, U3, V0, V1, V2, V3);
        L1_STEP(s + 1, 1, ypfB, V0, V1, V2, V3, U0, U1, U2, U3);
    }
#undef L1_STEP

    if (kg == 0) {
        cstate[(size_t)b * HID + hid] = cc;
        hstate[(size_t)b * HID + hid] = hv;   // final h1 (fc reads this)
    }
}

// ===================== Final FC =====================
__global__ __launch_bounds__(128) void fc_kernel(
    const float* __restrict__ h1, const float* __restrict__ Wfc,
    const float* __restrict__ bfc, float* __restrict__ out)
{
    const int b = blockIdx.x;
    const int o = threadIdx.x;
    __shared__ float hs[HID];
    hs[o] = h1[(size_t)b * HID + o];
    __syncthreads();
    if (o < NOUT) {
        const float4* w  = reinterpret_cast<const float4*>(Wfc + (size_t)o * HID);
        const float4* hv = reinterpret_cast<const float4*>(hs);
        float acc = bfc[o];
        #pragma unroll
        for (int q = 0; q < HID / 4; ++q) {
            float4 wv = w[q]; float4 h4 = hv[q];
            acc = fmaf(wv.x, h4.x, fmaf(wv.y, h4.y, fmaf(wv.z, h4.z, fmaf(wv.w, h4.w, acc))));
        }
        out[(size_t)b * NOUT + o] = acc;
    }
}

extern "C" void kernel_launch(void* const* d_in, const int* in_sizes, int n_in,
                              void* d_out, int out_size, void* d_ws, size_t ws_size,
                              hipStream_t stream) {
    const float* x    = (const float*)d_in[0];
    const float* Wih0 = (const float*)d_in[1];
    const float* Whh0 = (const float*)d_in[2];
    const float* bih0 = (const float*)d_in[3];
    const float* bhh0 = (const float*)d_in[4];
    const float* Wih1 = (const float*)d_in[5];
    const float* Whh1 = (const float*)d_in[6];
    const float* bih1 = (const float*)d_in[7];
    const float* bhh1 = (const float*)d_in[8];
    const float* Wfc  = (const float*)d_in[9];
    const float* bfc  = (const float*)d_in[10];
    float* out = (float*)d_out;

    // ws: hst0 | cst0 | hst1 | cst1 (f32, 128KB each) then y0 slab (f16)
    float* hst0 = (float*)d_ws;
    float* cst0 = hst0 + BATCH * HID;
    float* hst1 = cst0 + BATCH * HID;
    float* cst1 = hst1 + BATCH * HID;
    _Float16* y0 = (_Float16*)(cst1 + BATCH * HID);

    const size_t stateBytes = (size_t)4 * BATCH * HID * sizeof(float);   // 512 KB
    size_t avail = ws_size > stateBytes ? ws_size - stateBytes : 0;
    int Tc = (int)(avail / ((size_t)BATCH * HID * 2));
    if (Tc > TLEN) Tc = TLEN;
    Tc &= ~1;
    if (Tc < 2) Tc = 2;

    hipMemsetAsync(d_ws, 0, stateBytes, stream);

    for (int t0 = 0; t0 < TLEN; t0 += Tc) {
        int t1 = t0 + Tc; if (t1 > TLEN) t1 = TLEN;
        lstm_l0<<<BATCH, 512, 0, stream>>>(x, Wih0, Whh0, bih0, bhh0, hst0, cst0, y0, t0, t1);
        lstm_l1<<<BATCH, 512, 0, stream>>>(y0, Wih1, Whh1, bih1, bhh1, hst1, cst1, t0, t1);
    }
    fc_kernel<<<BATCH, 128, 0, stream>>>(hst1, Wfc, bfc, out);
}